// Round 13
// baseline (271.361 us; speedup 1.0000x reference)
//
#include <hip/hip_runtime.h>
#include <hip/hip_cooperative_groups.h>
#include <stdint.h>

namespace cg = cooperative_groups;

typedef __bf16 bf16x8 __attribute__((ext_vector_type(8)));
typedef float  f32x4  __attribute__((ext_vector_type(4)));
typedef uint32_t u32x4 __attribute__((ext_vector_type(4)));

__device__ __forceinline__ uint16_t f2bf(float f) {
    uint32_t u = __builtin_bit_cast(uint32_t, f);
    u += 0x7FFFu + ((u >> 16) & 1u);          // round-to-nearest-even
    return (uint16_t)(u >> 16);
}

// ---------------------------------------------------------------------------
// FUSED cooperative kernel, grid 1024 (= exactly resident: 4 blocks/CU),
// block bid -> b = bid&15 (XCD swizzle), d = bid>>4.
// Phase Q (pre-sync): each block transposes ONE c-octet x j-half of Q[b]
//   (ch = d>>1, jh = d&1) into Qt -- 1024-way split of the old 512-block
//   qtrans, loads 64B-line coalesced, writes 256B dense.  Qt[b] is written
//   and read on the same XCD (bid = b mod 16 => XCD b%8) -> L2-local.
// Phase S (pre-sync): zero-pad + stage S[b,:,d,:] into LDS (r12 verbatim).
// grid.sync()  -- Qt complete and visible.
// Phase C (post-sync): r12 corr body BYTE-IDENTICAL (B ping-pong +
//   sched_barrier(0) + setprio + swizzled Pw epilogue + atomics).
// REGISTER DISCIPLINE (r1/r8/r10 law): live state beyond acc(40 AGPR) +
// ONE ping-pong set(32) + A(20) + addressing spills at (256,4).
// ---------------------------------------------------------------------------
__global__ __launch_bounds__(256, 4) void fused_kernel(const float* __restrict__ Q,
                                                       const float* __restrict__ S,
                                                       uint16_t* __restrict__ Qt,
                                                       float* __restrict__ out) {
    __shared__ __align__(16) char smem[40960];         // T overlay / S_l / Pw
    const int bid = blockIdx.x;
    const int b = bid & 15, d = bid >> 4;
    const int tid = threadIdx.x, wave = tid >> 6, lane = tid & 63;
    const int l15 = lane & 15, l4 = lane >> 4;

    // ---- phase 0: zero the output (1024*256 = 262144 >= 67600)
    { int g = bid * 256 + tid; if (g < 67600) out[g] = 0.f; }

    // ---- phase Q: transpose c-octet (d>>1), j-half (d&1) of Q[b] -> Qt
    {
        float* T = (float*)smem;                       // [c8 8][i 32][jl 17] pad-545
        const int ch = d >> 1, jh = d & 1;
        const float* src = Q + ((size_t)(b * 256 + ch * 8)) * 1024;
        #pragma unroll
        for (int it = 0; it < 16; ++it) {              // 4096 f32, 64B-coalesced
            int r = tid + it * 256;
            int c8 = r >> 9, rem = r & 511;
            int i = rem >> 4, jl = rem & 15;
            T[c8 * 545 + i * 17 + jl] = src[(size_t)c8 * 1024 + i * 32 + jh * 16 + jl];
        }
        __syncthreads();
        uint32_t* dst = (uint32_t*)Qt;
        #pragma unroll
        for (int it = 0; it < 8; ++it) {               // 2048 pair-writes, 256B dense
            int o2 = tid + it * 256;
            int p  = o2 & 3;                           // t-pair index
            int il = (o2 >> 2) & 15;
            int jl = (o2 >> 6) & 15;
            int ih = (o2 >> 10) & 1;
            float v0 = T[(2 * p) * 545 + (ih * 16 + il) * 17 + jl];
            float v1 = T[(2 * p + 1) * 545 + (ih * 16 + il) * 17 + jl];
            uint32_t pk = (uint32_t)f2bf(v0) | ((uint32_t)f2bf(v1) << 16);
            int j = jh * 16 + jl;
            size_t oi = ((((size_t)(b * 2 + ih) * 32 + j) * 32 + ch) * 16 + il) * 4 + p;
            dst[oi] = pk;
        }
        __syncthreads();                               // T dead before S_l reuse
    }

    uint16_t* S_l = (uint16_t*)smem;                   // [ch][row]: ch*640 + row*8
    float*    Pw  = (float*)smem;                      // overlay: [4][iv 32][x 80]

    // ---- phase S: zero-fill pad rows 0..15 (8 KB) + stage S[b,:,d,:] (bf16)
    {
        const u32x4 z = {};
        for (int zi = tid; zi < 512; zi += 256) {
            int ch = zi >> 4, r = zi & 15;
            *(u32x4*)&S_l[ch * 640 + r * 8] = z;
        }
    }
    {
        const int sx = tid & 63, w = tid >> 6;
        const float* sp = S + ((size_t)b * 256) * 4096 + (size_t)d * 64;
        #pragma unroll
        for (int k = 0; k < 8; ++k) {
            int ch = w * 8 + k;
            float v[8];
            #pragma unroll
            for (int cc = 0; cc < 8; ++cc)
                v[cc] = sp[(size_t)(ch * 8 + cc) * 4096 + sx];   // 256B coalesced
            u32x4 pk;
            #pragma unroll
            for (int q = 0; q < 4; ++q)
                pk[q] = (uint32_t)f2bf(v[2 * q]) | ((uint32_t)f2bf(v[2 * q + 1]) << 16);
            *(u32x4*)&S_l[ch * 640 + (sx + 16) * 8] = pk;        // contiguous 1KB/wave
        }
    }

    // ---- grid-wide barrier: all Qt writes complete & visible
    cg::this_grid().sync();

    // ---- phase C: r12 corr body (unchanged)
    const uint16_t* Bb = Qt + (size_t)b * 262144 + l4 * 128 + l15 * 8;

    bf16x8 C0, C1, C2, C3;
    {
        const int s0 = (2 * wave) & 7;
        const uint16_t* p0 = Bb + wave * 4096 + s0 * 512;
        C0 = *(const bf16x8*)(p0);
        C1 = *(const bf16x8*)(p0 + 131072);
        C2 = *(const bf16x8*)(p0 + 65536);
        C3 = *(const bf16x8*)(p0 + 196608);
    }

    f32x4 acc[5][2] = {};

    #pragma unroll
    for (int n = 0; n < 32; ++n) {
        const int jj = n >> 3;
        const int s  = ((n & 7) + 2 * wave) & 7;       // per-wave s-rotation
        const int j0a = wave + jj * 4;                 // 0..15 ; j0b = j0a+16

        const int nn = (n < 31) ? (n + 1) : 31;
        const int jn = nn >> 3;
        const int sn = ((nn & 7) + 2 * wave) & 7;
        const uint16_t* pn = Bb + (wave + jn * 4) * 4096 + sn * 512;
        bf16x8 N0 = *(const bf16x8*)(pn);
        bf16x8 N1 = *(const bf16x8*)(pn + 131072);
        bf16x8 N2 = *(const bf16x8*)(pn + 65536);
        bf16x8 N3 = *(const bf16x8*)(pn + 196608);

        const int chb = (s * 4 + l4) * 640;
        bf16x8 A[5];
        #pragma unroll
        for (int t = 0; t < 5; ++t) {
            int rr = j0a + t * 16 + l15;               // <= 94
            rr = (rr < 80) ? rr : 0;                   // OOB -> zero-row
            A[t] = *(const bf16x8*)&S_l[chb + rr * 8];
        }
        __builtin_amdgcn_sched_barrier(0);             // do NOT sink the loads

        __builtin_amdgcn_s_setprio(1);
        #pragma unroll
        for (int t = 0; t < 5; ++t) {
            acc[t][0] = __builtin_amdgcn_mfma_f32_16x16x32_bf16(A[t], C0, acc[t][0], 0, 0, 0);
            acc[t][1] = __builtin_amdgcn_mfma_f32_16x16x32_bf16(A[t], C1, acc[t][1], 0, 0, 0);
        }
        #pragma unroll
        for (int t = 1; t < 5; ++t) {
            acc[t - 1][0] = __builtin_amdgcn_mfma_f32_16x16x32_bf16(A[t], C2, acc[t - 1][0], 0, 0, 0);
            acc[t - 1][1] = __builtin_amdgcn_mfma_f32_16x16x32_bf16(A[t], C3, acc[t - 1][1], 0, 0, 0);
        }
        __builtin_amdgcn_s_setprio(0);

        C0 = N0; C1 = N1; C2 = N2; C3 = N3;
    }

    // ---- merge 4 wave-partials in LDS (XOR-swizzled groups), then atomics
    __syncthreads();
    {
        float* pw = Pw + wave * 2560;                  // [iv 32][x 80], swizzled
        #pragma unroll
        for (int m = 0; m < 5; ++m)
            #pragma unroll
            for (int n = 0; n < 2; ++n) {
                const int row = n * 16 + l15;
                const int grp = m * 4 + (l4 ^ (l15 & 3));   // stored = logical^(row&3)
                *(f32x4*)&pw[row * 80 + grp * 4] = acc[m][n];
            }
    }
    __syncthreads();
    for (int e = tid; e < 65 * 32; e += 256) {
        int x = e % 65, i = e / 65;
        int y = d - i + 16;
        if ((unsigned)y < 65u) {
            const int gx = ((((x >> 2) ^ (i & 3)) << 2) | (x & 3));  // un-swizzle
            const int o  = i * 80 + gx;
            float v = Pw[0 * 2560 + o] + Pw[1 * 2560 + o]
                    + Pw[2 * 2560 + o] + Pw[3 * 2560 + o];
            atomicAdd(out + ((size_t)b * 4225 + (size_t)y * 65 + x), v);
        }
    }
}

// ---------------------------------------------------------------------------
// Fallback two-kernel path (r12, proven 130.9 us) if cooperative launch fails
// ---------------------------------------------------------------------------
__global__ __launch_bounds__(256) void qtrans_kernel(const float* __restrict__ Q,
                                                     uint16_t* __restrict__ Qt,
                                                     float* __restrict__ out) {
    __shared__ float T[8 * 1064];
    const int ch = blockIdx.x, b = blockIdx.y;
    const int tid = threadIdx.x;
    {
        int g = (b * 32 + ch) * 256 + tid;
        if (g < 67600) out[g] = 0.f;
    }
    const float* src = Q + ((size_t)(b * 256 + ch * 8)) * 1024;
    #pragma unroll
    for (int it = 0; it < 32; ++it) {
        int r = tid + it * 256;
        int c8 = r >> 10, rem = r & 1023;
        T[c8 * 1064 + (rem >> 5) * 33 + (rem & 31)] = src[(size_t)c8 * 1024 + rem];
    }
    __syncthreads();
    uint32_t* dst = (uint32_t*)Qt;
    #pragma unroll
    for (int it = 0; it < 16; ++it) {
        int o2 = tid + it * 256;
        int t  = (o2 & 3) * 2;
        int il = (o2 >> 2) & 15;
        int j  = (o2 >> 6) & 31;
        int ih = (o2 >> 11) & 1;
        float v0 = T[t * 1064 + (ih * 16 + il) * 33 + j];
        float v1 = T[(t + 1) * 1064 + (ih * 16 + il) * 33 + j];
        uint32_t pk = (uint32_t)f2bf(v0) | ((uint32_t)f2bf(v1) << 16);
        size_t oi = ((((size_t)(b * 2 + ih) * 32 + j) * 32 + ch) * 16 + il) * 4 + (t >> 1);
        dst[oi] = pk;
    }
}

__global__ __launch_bounds__(256, 4) void corr_kernel(const float* __restrict__ S,
                                                      const uint16_t* __restrict__ Qt,
                                                      float* __restrict__ out) {
    __shared__ __align__(16) char smem[40960];
    uint16_t* S_l = (uint16_t*)smem;
    float*    Pw  = (float*)smem;

    const int bid = blockIdx.x;
    const int b = bid & 15, d = bid >> 4;
    const int tid = threadIdx.x, wave = tid >> 6, lane = tid & 63;
    const int l15 = lane & 15, l4 = lane >> 4;

    {
        const u32x4 z = {};
        for (int zi = tid; zi < 512; zi += 256) {
            int ch = zi >> 4, r = zi & 15;
            *(u32x4*)&S_l[ch * 640 + r * 8] = z;
        }
    }
    {
        const int sx = tid & 63, w = tid >> 6;
        const float* sp = S + ((size_t)b * 256) * 4096 + (size_t)d * 64;
        #pragma unroll
        for (int k = 0; k < 8; ++k) {
            int ch = w * 8 + k;
            float v[8];
            #pragma unroll
            for (int cc = 0; cc < 8; ++cc)
                v[cc] = sp[(size_t)(ch * 8 + cc) * 4096 + sx];
            u32x4 pk;
            #pragma unroll
            for (int q = 0; q < 4; ++q)
                pk[q] = (uint32_t)f2bf(v[2 * q]) | ((uint32_t)f2bf(v[2 * q + 1]) << 16);
            *(u32x4*)&S_l[ch * 640 + (sx + 16) * 8] = pk;
        }
    }

    const uint16_t* Bb = Qt + (size_t)b * 262144 + l4 * 128 + l15 * 8;
    bf16x8 C0, C1, C2, C3;
    {
        const int s0 = (2 * wave) & 7;
        const uint16_t* p0 = Bb + wave * 4096 + s0 * 512;
        C0 = *(const bf16x8*)(p0);
        C1 = *(const bf16x8*)(p0 + 131072);
        C2 = *(const bf16x8*)(p0 + 65536);
        C3 = *(const bf16x8*)(p0 + 196608);
    }
    __syncthreads();

    f32x4 acc[5][2] = {};
    #pragma unroll
    for (int n = 0; n < 32; ++n) {
        const int jj = n >> 3;
        const int s  = ((n & 7) + 2 * wave) & 7;
        const int j0a = wave + jj * 4;
        const int nn = (n < 31) ? (n + 1) : 31;
        const int jn = nn >> 3;
        const int sn = ((nn & 7) + 2 * wave) & 7;
        const uint16_t* pn = Bb + (wave + jn * 4) * 4096 + sn * 512;
        bf16x8 N0 = *(const bf16x8*)(pn);
        bf16x8 N1 = *(const bf16x8*)(pn + 131072);
        bf16x8 N2 = *(const bf16x8*)(pn + 65536);
        bf16x8 N3 = *(const bf16x8*)(pn + 196608);

        const int chb = (s * 4 + l4) * 640;
        bf16x8 A[5];
        #pragma unroll
        for (int t = 0; t < 5; ++t) {
            int rr = j0a + t * 16 + l15;
            rr = (rr < 80) ? rr : 0;
            A[t] = *(const bf16x8*)&S_l[chb + rr * 8];
        }
        __builtin_amdgcn_sched_barrier(0);

        __builtin_amdgcn_s_setprio(1);
        #pragma unroll
        for (int t = 0; t < 5; ++t) {
            acc[t][0] = __builtin_amdgcn_mfma_f32_16x16x32_bf16(A[t], C0, acc[t][0], 0, 0, 0);
            acc[t][1] = __builtin_amdgcn_mfma_f32_16x16x32_bf16(A[t], C1, acc[t][1], 0, 0, 0);
        }
        #pragma unroll
        for (int t = 1; t < 5; ++t) {
            acc[t - 1][0] = __builtin_amdgcn_mfma_f32_16x16x32_bf16(A[t], C2, acc[t - 1][0], 0, 0, 0);
            acc[t - 1][1] = __builtin_amdgcn_mfma_f32_16x16x32_bf16(A[t], C3, acc[t - 1][1], 0, 0, 0);
        }
        __builtin_amdgcn_s_setprio(0);

        C0 = N0; C1 = N1; C2 = N2; C3 = N3;
    }

    __syncthreads();
    {
        float* pw = Pw + wave * 2560;
        #pragma unroll
        for (int m = 0; m < 5; ++m)
            #pragma unroll
            for (int n = 0; n < 2; ++n) {
                const int row = n * 16 + l15;
                const int grp = m * 4 + (l4 ^ (l15 & 3));
                *(f32x4*)&pw[row * 80 + grp * 4] = acc[m][n];
            }
    }
    __syncthreads();
    for (int e = tid; e < 65 * 32; e += 256) {
        int x = e % 65, i = e / 65;
        int y = d - i + 16;
        if ((unsigned)y < 65u) {
            const int gx = ((((x >> 2) ^ (i & 3)) << 2) | (x & 3));
            const int o  = i * 80 + gx;
            float v = Pw[0 * 2560 + o] + Pw[1 * 2560 + o]
                    + Pw[2 * 2560 + o] + Pw[3 * 2560 + o];
            atomicAdd(out + ((size_t)b * 4225 + (size_t)y * 65 + x), v);
        }
    }
}

// ---------------------------------------------------------------------------
// fp32 fallback (only if workspace is too small) — slow but exact
// ---------------------------------------------------------------------------
__global__ __launch_bounds__(256) void naive_kernel(const float* __restrict__ Q,
                                                    const float* __restrict__ S,
                                                    float* __restrict__ out) {
    int gid = blockIdx.x * 256 + threadIdx.x;
    if (gid >= 67600) return;
    int b = gid / 4225, r = gid % 4225, y = r / 65, x = r % 65;
    int jlo = 16 - x; if (jlo < 0) jlo = 0;
    int jhi = 80 - x; if (jhi > 32) jhi = 32;
    float acc = 0.f;
    for (int c = 0; c < 256; ++c) {
        const float* Sb = S + ((size_t)(b * 256 + c)) * 4096;
        const float* Qb = Q + ((size_t)(b * 256 + c)) * 1024;
        for (int i = 0; i < 32; ++i) {
            int dd = y + i - 16;
            if ((unsigned)dd >= 64u) continue;
            const float* Sr = Sb + dd * 64 + (x - 16);
            const float* Qr = Qb + i * 32;
            for (int j = jlo; j < jhi; ++j) acc += Sr[j] * Qr[j];
        }
    }
    out[gid] = acc;
}

extern "C" void kernel_launch(void* const* d_in, const int* in_sizes, int n_in,
                              void* d_out, int out_size, void* d_ws, size_t ws_size,
                              hipStream_t stream) {
    (void)in_sizes; (void)n_in; (void)out_size;
    const float* Q = (const float*)d_in[0];   // [16,256,32,32] f32
    const float* S = (const float*)d_in[1];   // [16,256,64,64] f32
    float* out = (float*)d_out;               // [16,1,65,65] f32

    const size_t QT_BYTES = (size_t)16 * 2 * 32 * 32 * 16 * 8 * 2;  // 8,388,608

    if (ws_size < QT_BYTES) {
        naive_kernel<<<(67600 + 255) / 256, 256, 0, stream>>>(Q, S, out);
        return;
    }
    uint16_t* Qt = (uint16_t*)d_ws;

    void* kargs[] = {(void*)&Q, (void*)&S, (void*)&Qt, (void*)&out};
    hipError_t err = hipLaunchCooperativeKernel((const void*)fused_kernel,
                                                dim3(1024), dim3(256),
                                                kargs, 0, stream);
    if (err != hipSuccess) {
        // fallback: proven r12 two-kernel path
        qtrans_kernel<<<dim3(32, 16), 256, 0, stream>>>(Q, Qt, out);
        corr_kernel<<<1024, 256, 0, stream>>>(S, Qt, out);
    }
}

// Round 14
// 133.975 us; speedup vs baseline: 2.0255x; 2.0255x over previous
//
#include <hip/hip_runtime.h>
#include <stdint.h>

typedef __bf16 bf16x8 __attribute__((ext_vector_type(8)));
typedef float  f32x4  __attribute__((ext_vector_type(4)));
typedef uint32_t u32x4 __attribute__((ext_vector_type(4)));

__device__ __forceinline__ uint16_t f2bf(float f) {
    uint32_t u = __builtin_bit_cast(uint32_t, f);
    u += 0x7FFFu + ((u >> 16) & 1u);          // round-to-nearest-even
    return (uint16_t)(u >> 16);
}

// ---------------------------------------------------------------------------
// Kernel 1 (1024-block split, salvaged from r13's passing fused run):
// grid (64,16): q = blockIdx.x -> ch = q>>1 (c-octet), jh = q&1 (j-half);
// b = blockIdx.y.  Q [b][c 256][i 32][j 32] f32 ->
// Qt [b][ih 2][j 32][ch 32][il 16][8] bf16  (c = ch*8+t, i = ih*16+il).
// 17 KB LDS -> ~9 blocks/CU (vs 34 KB/4 in the old 512-block version).
// Also zeroes the output tensor (1024*256 = 262144 >= 67600).
// ---------------------------------------------------------------------------
__global__ __launch_bounds__(256) void qtrans_kernel(const float* __restrict__ Q,
                                                     uint16_t* __restrict__ Qt,
                                                     float* __restrict__ out) {
    __shared__ float T[8 * 545];                       // [c8 8][i 32][jl 17]
    const int q = blockIdx.x, b = blockIdx.y;
    const int ch = q >> 1, jh = q & 1;
    const int tid = threadIdx.x;

    { int g = (b * 64 + q) * 256 + tid; if (g < 67600) out[g] = 0.f; }

    const float* src = Q + ((size_t)(b * 256 + ch * 8)) * 1024;
    #pragma unroll
    for (int it = 0; it < 16; ++it) {                  // 4096 f32, 64B-coalesced
        int r = tid + it * 256;
        int c8 = r >> 9, rem = r & 511;
        int i = rem >> 4, jl = rem & 15;
        T[c8 * 545 + i * 17 + jl] = src[(size_t)c8 * 1024 + i * 32 + jh * 16 + jl];
    }
    __syncthreads();

    uint32_t* dst = (uint32_t*)Qt;                     // write bf16 pairs
    #pragma unroll
    for (int it = 0; it < 8; ++it) {                   // 2048 pair-writes, 256B dense
        int o2 = tid + it * 256;
        int p  = o2 & 3;                               // t-pair index (t = 2p)
        int il = (o2 >> 2) & 15;
        int jl = (o2 >> 6) & 15;
        int ih = (o2 >> 10) & 1;
        float v0 = T[(2 * p) * 545 + (ih * 16 + il) * 17 + jl];
        float v1 = T[(2 * p + 1) * 545 + (ih * 16 + il) * 17 + jl];
        uint32_t pk = (uint32_t)f2bf(v0) | ((uint32_t)f2bf(v1) << 16);
        int j = jh * 16 + jl;
        size_t oi = ((((size_t)(b * 2 + ih) * 32 + j) * 32 + ch) * 16 + il) * 4 + p;
        dst[oi] = pk;
    }
}

// ---------------------------------------------------------------------------
// Kernel 2: r12 BYTE-IDENTICAL (proven best: 44.6 us steady, 868 TF = 35% of
// dense peak = the documented non-deep-pipeline structure ceiling).
// Structure: grid 1024, b=bid&15 XCD swizzle, 40 KB LDS, 4 blocks/CU,
// B-fragment ping-pong + sched_barrier(0), setprio around MFMA cluster,
// XOR-swizzled Pw epilogue.  CLOSED LANES (do not revisit): occupancy
// (r2/r4/r5), A-prefetch & staging-in-reg (r1/r8/r10 spill), SGB (r9),
// grid.sync fusion (r13).
// ---------------------------------------------------------------------------
__global__ __launch_bounds__(256, 4) void corr_kernel(const float* __restrict__ S,
                                                      const uint16_t* __restrict__ Qt,
                                                      float* __restrict__ out) {
    __shared__ __align__(16) char smem[40960];         // 40 KB -> 4 blocks/CU
    uint16_t* S_l = (uint16_t*)smem;                   // [ch][row]: idx = ch*640 + row*8
    float*    Pw  = (float*)smem;                      // overlay: [4][iv 32][x 80]

    const int bid = blockIdx.x;
    const int b = bid & 15, d = bid >> 4;
    const int tid = threadIdx.x, wave = tid >> 6, lane = tid & 63;
    const int l15 = lane & 15, l4 = lane >> 4;

    // ---- zero-fill pad rows 0..15 for all ch (8 KB)
    {
        const u32x4 z = {};
        for (int zi = tid; zi < 512; zi += 256) {
            int ch = zi >> 4, r = zi & 15;
            *(u32x4*)&S_l[ch * 640 + r * 8] = z;
        }
    }
    // ---- stage S[b,:,d,:] -> S_l[ch][sx+16] (bf16). Writes lane-contiguous.
    {
        const int sx = tid & 63, w = tid >> 6;
        const float* sp = S + ((size_t)b * 256) * 4096 + (size_t)d * 64;
        #pragma unroll
        for (int k = 0; k < 8; ++k) {
            int ch = w * 8 + k;
            float v[8];
            #pragma unroll
            for (int cc = 0; cc < 8; ++cc)
                v[cc] = sp[(size_t)(ch * 8 + cc) * 4096 + sx];   // 256B coalesced
            u32x4 pk;
            #pragma unroll
            for (int qq = 0; qq < 4; ++qq)
                pk[qq] = (uint32_t)f2bf(v[2 * qq]) | ((uint32_t)f2bf(v[2 * qq + 1]) << 16);
            *(u32x4*)&S_l[ch * 640 + (sx + 16) * 8] = pk;        // contiguous 1KB/wave
        }
    }

    // ---- B-fragment base.  Body (jj,s): off = (wave+jj*4)*4096 + s*512.
    const uint16_t* Bb = Qt + (size_t)b * 262144 + l4 * 128 + l15 * 8;

    // prefetch body 0's B-fragments BEFORE the barrier (no LDS dependency)
    bf16x8 C0, C1, C2, C3;
    {
        const int s0 = (2 * wave) & 7;
        const uint16_t* p0 = Bb + wave * 4096 + s0 * 512;
        C0 = *(const bf16x8*)(p0);
        C1 = *(const bf16x8*)(p0 + 131072);
        C2 = *(const bf16x8*)(p0 + 65536);
        C3 = *(const bf16x8*)(p0 + 196608);
    }

    __syncthreads();

    f32x4 acc[5][2] = {};

    #pragma unroll
    for (int n = 0; n < 32; ++n) {
        const int jj = n >> 3;
        const int s  = ((n & 7) + 2 * wave) & 7;       // per-wave s-rotation
        const int j0a = wave + jj * 4;                 // 0..15 ; j0b = j0a+16

        const int nn = (n < 31) ? (n + 1) : 31;
        const int jn = nn >> 3;
        const int sn = ((nn & 7) + 2 * wave) & 7;
        const uint16_t* pn = Bb + (wave + jn * 4) * 4096 + sn * 512;
        bf16x8 N0 = *(const bf16x8*)(pn);
        bf16x8 N1 = *(const bf16x8*)(pn + 131072);
        bf16x8 N2 = *(const bf16x8*)(pn + 65536);
        bf16x8 N3 = *(const bf16x8*)(pn + 196608);

        const int chb = (s * 4 + l4) * 640;
        bf16x8 A[5];
        #pragma unroll
        for (int t = 0; t < 5; ++t) {
            int rr = j0a + t * 16 + l15;               // <= 94
            rr = (rr < 80) ? rr : 0;                   // OOB -> zero-row
            A[t] = *(const bf16x8*)&S_l[chb + rr * 8];
        }
        __builtin_amdgcn_sched_barrier(0);             // do NOT sink the loads

        __builtin_amdgcn_s_setprio(1);
        #pragma unroll
        for (int t = 0; t < 5; ++t) {
            acc[t][0] = __builtin_amdgcn_mfma_f32_16x16x32_bf16(A[t], C0, acc[t][0], 0, 0, 0);
            acc[t][1] = __builtin_amdgcn_mfma_f32_16x16x32_bf16(A[t], C1, acc[t][1], 0, 0, 0);
        }
        #pragma unroll
        for (int t = 1; t < 5; ++t) {
            acc[t - 1][0] = __builtin_amdgcn_mfma_f32_16x16x32_bf16(A[t], C2, acc[t - 1][0], 0, 0, 0);
            acc[t - 1][1] = __builtin_amdgcn_mfma_f32_16x16x32_bf16(A[t], C3, acc[t - 1][1], 0, 0, 0);
        }
        __builtin_amdgcn_s_setprio(0);

        C0 = N0; C1 = N1; C2 = N2; C3 = N3;
    }

    // ---- merge 4 wave-partials in LDS (XOR-swizzled groups), then atomics
    __syncthreads();
    {
        float* pw = Pw + wave * 2560;                  // [iv 32][x 80], swizzled
        #pragma unroll
        for (int m = 0; m < 5; ++m)
            #pragma unroll
            for (int n = 0; n < 2; ++n) {
                const int row = n * 16 + l15;
                const int grp = m * 4 + (l4 ^ (l15 & 3));   // stored = logical^(row&3)
                *(f32x4*)&pw[row * 80 + grp * 4] = acc[m][n];
            }
    }
    __syncthreads();
    for (int e = tid; e < 65 * 32; e += 256) {
        int x = e % 65, i = e / 65;
        int y = d - i + 16;
        if ((unsigned)y < 65u) {
            const int gx = ((((x >> 2) ^ (i & 3)) << 2) | (x & 3));  // un-swizzle
            const int o  = i * 80 + gx;
            float v = Pw[0 * 2560 + o] + Pw[1 * 2560 + o]
                    + Pw[2 * 2560 + o] + Pw[3 * 2560 + o];
            atomicAdd(out + ((size_t)b * 4225 + (size_t)y * 65 + x), v);
        }
    }
}

// ---------------------------------------------------------------------------
// fp32 fallback (only if workspace is too small) — slow but exact
// ---------------------------------------------------------------------------
__global__ __launch_bounds__(256) void naive_kernel(const float* __restrict__ Q,
                                                    const float* __restrict__ S,
                                                    float* __restrict__ out) {
    int gid = blockIdx.x * 256 + threadIdx.x;
    if (gid >= 67600) return;
    int b = gid / 4225, r = gid % 4225, y = r / 65, x = r % 65;
    int jlo = 16 - x; if (jlo < 0) jlo = 0;
    int jhi = 80 - x; if (jhi > 32) jhi = 32;
    float acc = 0.f;
    for (int c = 0; c < 256; ++c) {
        const float* Sb = S + ((size_t)(b * 256 + c)) * 4096;
        const float* Qb = Q + ((size_t)(b * 256 + c)) * 1024;
        for (int i = 0; i < 32; ++i) {
            int dd = y + i - 16;
            if ((unsigned)dd >= 64u) continue;
            const float* Sr = Sb + dd * 64 + (x - 16);
            const float* Qr = Qb + i * 32;
            for (int j = jlo; j < jhi; ++j) acc += Sr[j] * Qr[j];
        }
    }
    out[gid] = acc;
}

extern "C" void kernel_launch(void* const* d_in, const int* in_sizes, int n_in,
                              void* d_out, int out_size, void* d_ws, size_t ws_size,
                              hipStream_t stream) {
    (void)in_sizes; (void)n_in; (void)out_size;
    const float* Q = (const float*)d_in[0];   // [16,256,32,32] f32
    const float* S = (const float*)d_in[1];   // [16,256,64,64] f32
    float* out = (float*)d_out;               // [16,1,65,65] f32

    const size_t QT_BYTES = (size_t)16 * 2 * 32 * 32 * 16 * 8 * 2;  // 8,388,608

    if (ws_size < QT_BYTES) {
        naive_kernel<<<(67600 + 255) / 256, 256, 0, stream>>>(Q, S, out);
        return;
    }
    uint16_t* Qt = (uint16_t*)d_ws;

    qtrans_kernel<<<dim3(64, 16), 256, 0, stream>>>(Q, Qt, out);
    corr_kernel<<<1024, 256, 0, stream>>>(S, Qt, out);
}